// Round 16
// baseline (426.700 us; speedup 1.0000x reference)
//
#include <hip/hip_runtime.h>
#include <hip/hip_fp8.h>
#include <math.h>

// ---------------------------------------------------------------------------
// AGNN round 16:
//  - conv re-geometried to 8 lanes/edge x 8 edges/round. r6's version of this
//    failed on bf16 (2 dependent uint4 loads/lane + divergent predication);
//    fp8 rows (r14) are 128B = ONE uint4/lane at the 16B sweet spot. Keeps
//    the verified r10/r12 skeleton: chunked 64-idx batch (now covers 8
//    rounds), 2-deep row pipe, clamp predication, same math order.
//  - k_detect folded into k_cvt (per-block wave-0 ballot) -> one less launch
// gemm1 = r15 4-slot loop-carried pipeline (verified). Rest = r15.
// ---------------------------------------------------------------------------

static inline int divup(int a, int b) { return (a + b - 1) / b; }

typedef __attribute__((ext_vector_type(8))) short short8;
typedef __attribute__((ext_vector_type(4))) float f32x4;
union U16 { uint4 u; short8 s; };

__device__ __forceinline__ unsigned bf16r(float f) {  // f32 -> bf16 bits, RNE
    unsigned u = __float_as_uint(f);
    return (u + 0x7FFFu + ((u >> 16) & 1u)) >> 16;
}
__device__ __forceinline__ unsigned pack2(float a, float b) {
    return bf16r(a) | (bf16r(b) << 16);
}
__device__ __forceinline__ float bflo(unsigned u) { return __uint_as_float(u << 16); }
__device__ __forceinline__ float bfhi(unsigned u) { return __uint_as_float(u & 0xFFFF0000u); }

__device__ __forceinline__ unsigned char fp8e(float f) {
    __hip_fp8_e4m3 q(f);
    return (unsigned char)q.__x;
}
__device__ __forceinline__ float fp8d(unsigned char b) {
    __hip_fp8_e4m3 q;
    q.__x = (__hip_fp8_storage_t)b;
    return (float)q;
}
__device__ __forceinline__ void unpf16(uint4 u, float* v) {
    const unsigned char* b = (const unsigned char*)&u;
#pragma unroll
    for (int i = 0; i < 16; ++i) v[i] = fp8d(b[i]);
}

// --- edge convert (+dtype autodetect per block, +histogram fold) -----------
__global__ __launch_bounds__(256) void k_cvt(const int* __restrict__ raw, int E,
                                             int* __restrict__ s32, int* __restrict__ d32,
                                             int* __restrict__ cnt) {
    __shared__ int sflag;
    int tid = threadIdx.x;
    if (tid < 64) {
        int v = raw[2 * tid + 1];
        unsigned long long b = __ballot(v != 0);
        if (tid == 0) sflag = (b == 0ULL) ? 1 : 0;  // 1 => int64 layout
    }
    __syncthreads();
    int flag = sflag;
    int i = blockIdx.x * blockDim.x + tid;
    if (i >= E) return;
    int s, d;
    if (flag) {
        s = raw[2 * (size_t)i];
        d = raw[2 * ((size_t)E + i)];
    } else {
        s = raw[i];
        d = raw[(size_t)E + i];
    }
    s32[i] = s;
    d32[i] = d;
    atomicAdd(&cnt[d], 1);
}

// --- CSR scan (cnt + 1 self-loop per node) ---------------------------------
__global__ __launch_bounds__(1024) void k_scan1(const int* __restrict__ cnt, int N,
                                                int* __restrict__ rp, int* __restrict__ bsum) {
    __shared__ int sm[1024];
    int t = threadIdx.x;
    int i = blockIdx.x * 1024 + t;
    int v = (i < N) ? cnt[i] + 1 : 0;  // +1: self-loop
    sm[t] = v;
    __syncthreads();
#pragma unroll
    for (int off = 1; off < 1024; off <<= 1) {
        int u = (t >= off) ? sm[t - off] : 0;
        __syncthreads();
        sm[t] += u;
        __syncthreads();
    }
    if (i < N) rp[i] = sm[t] - v;  // exclusive
    if (t == 1023) bsum[blockIdx.x] = sm[t];
}

__global__ __launch_bounds__(64) void k_scan2(int* __restrict__ bsum, int nb) {
    if (threadIdx.x == 0) {
        int run = 0;
        for (int i = 0; i < nb; ++i) { int v = bsum[i]; bsum[i] = run; run += v; }
    }
}

__global__ __launch_bounds__(256) void k_scan3(int* __restrict__ rp, const int* __restrict__ bsum,
                                               int N, int Etot, int* __restrict__ cursor) {
    int i = blockIdx.x * blockDim.x + threadIdx.x;
    if (i < N) {
        int v = rp[i] + bsum[i >> 10];
        rp[i] = v;
        cursor[i] = v;
    } else if (i == N) {
        rp[N] = Etot;
    }
}

// --- XCD-partitioned scatter -----------------------------------------------
__global__ __launch_bounds__(256) void k_scatter(const int* __restrict__ s32,
                                                 const int* __restrict__ d32, int E, int N,
                                                 int* __restrict__ cursor,
                                                 int* __restrict__ esrc) {
    int b = blockIdx.x;
    int xcd = b & 7;
    int nstripe = gridDim.x >> 3;
    int stripe = b >> 3;
    int lo = (int)(((long long)xcd * N) >> 3);
    int hi = (int)(((long long)(xcd + 1) * N) >> 3);
    int Etot = E + N;
    for (int e = stripe * 256 + threadIdx.x; e < Etot; e += nstripe * 256) {
        int d = (e < E) ? d32[e] : (e - E);
        if (d < lo || d >= hi) continue;
        int s = (e < E) ? s32[e] : d;
        int pos = atomicAdd(&cursor[d], 1);
        esrc[pos] = s;
    }
}

// --- weight preconvert -----------------------------------------------------
__global__ __launch_bounds__(256) void k_cvtW1(const float* __restrict__ W1,
                                               unsigned short* __restrict__ W1t) {
    int i = blockIdx.x * 256 + threadIdx.x;
    if (i >= 512 * 128) return;
    int k = i >> 7, n = i & 127;
    W1t[n * 512 + k] = (unsigned short)bf16r(W1[i]);
}

__global__ __launch_bounds__(256) void k_cvtW2(const float* __restrict__ W2,
                                               unsigned short* __restrict__ W2t) {
    int i = blockIdx.x * 256 + threadIdx.x;
    if (i >= 128 * 64) return;
    int k = i >> 6, n = i & 63;
    W2t[n * 128 + k] = (unsigned short)bf16r(W2[i]);
}

// --- GEMM1: x_hat1(fp8)/norm1 = normalize(relu(x @ W1 + b1)) ---------------
// 64-row tile, W-resident in 4 phases of 128k (32KB LDS),
// A-stream: loop-carried 4-slot modulo pipeline (r15, verified).
#define XSW(c, off) ((off) ^ (((c) & 7) << 4))
__global__ __launch_bounds__(256) void k_gemm1(const float* __restrict__ x,
                                               const unsigned short* __restrict__ W1t,
                                               const float* __restrict__ b1, int N,
                                               unsigned char* __restrict__ xh1,
                                               float* __restrict__ n1) {
    __shared__ __align__(16) unsigned char lds[32768];
    const int tid = threadIdx.x;
    const int lane = tid & 63;
    const int lt = lane & 15, lg = lane >> 4;
    const int w = tid >> 6;
    const int row0 = blockIdx.x * 64;

    int arow = row0 + w * 16 + lt;
    if (arow > N - 1) arow = N - 1;
    const float* xb = x + (size_t)arow * 512 + lg * 8;

    f32x4 acc[8];
#pragma unroll
    for (int j = 0; j < 8; ++j) acc[j] = (f32x4){0.f, 0.f, 0.f, 0.f};

    float4 buf[4][2];
#pragma unroll
    for (int j = 0; j < 4; ++j) {
        buf[j][0] = ((const float4*)(xb + j * 32))[0];
        buf[j][1] = ((const float4*)(xb + j * 32))[1];
    }

#pragma unroll 1
    for (int kt = 0; kt < 4; ++kt) {
        const int kb = kt * 128;
        __syncthreads();
        {
            int c = tid >> 1, h = tid & 1;
            const uint4* wp = (const uint4*)(W1t + c * 512 + kb + h * 64);
            unsigned char* base = lds + c * 256;
#pragma unroll
            for (int i = 0; i < 8; ++i)
                *(uint4*)(base + XSW(c, h * 128 + i * 16)) = wp[i];
        }
        __syncthreads();

        const bool more = kt < 3;
#pragma unroll
        for (int j = 0; j < 4; ++j) {
            U16 af;
            af.u.x = pack2(buf[j][0].x, buf[j][0].y);
            af.u.y = pack2(buf[j][0].z, buf[j][0].w);
            af.u.z = pack2(buf[j][1].x, buf[j][1].y);
            af.u.w = pack2(buf[j][1].z, buf[j][1].w);
            if (more) {
                const float* np = xb + (kt + 1) * 128 + j * 32;
                buf[j][0] = ((const float4*)np)[0];
                buf[j][1] = ((const float4*)np)[1];
            }
#pragma unroll
            for (int cf = 0; cf < 8; ++cf) {
                int col = cf * 16 + lt;
                U16 bf;
                bf.u = *(const uint4*)(lds + col * 256 + XSW(col, j * 64 + lg * 16));
                acc[cf] = __builtin_amdgcn_mfma_f32_16x16x32_bf16(
                    af.s, bf.s, acc[cf], 0, 0, 0);
            }
        }
    }

    float bias[8];
#pragma unroll
    for (int cf = 0; cf < 8; ++cf) bias[cf] = b1[cf * 16 + lt];
    float* sc = (float*)lds;              // 32 rows x 132 f32 = 16896B
    unsigned char* pk = lds + 16896;      // 32 rows x 144B = 4608B
#pragma unroll 1
    for (int p = 0; p < 2; ++p) {
        __syncthreads();
        if ((w >> 1) == p) {
#pragma unroll
            for (int reg = 0; reg < 4; ++reg) {
                int rl = (w & 1) * 16 + lg * 4 + reg;
#pragma unroll
                for (int cf = 0; cf < 8; ++cf)
                    sc[rl * 132 + cf * 16 + lt] =
                        fmaxf(acc[cf][reg] + bias[cf], 0.f);
            }
        }
        __syncthreads();
        {
            int rl = tid >> 3, q = tid & 7;
            int gr = row0 + p * 32 + rl;
            const float* rowp = sc + rl * 132 + q * 16;
            float v[16];
#pragma unroll
            for (int i = 0; i < 4; ++i) {
                float4 f = ((const float4*)rowp)[i];
                v[4 * i] = f.x; v[4 * i + 1] = f.y; v[4 * i + 2] = f.z; v[4 * i + 3] = f.w;
            }
            float s2 = 0.f;
#pragma unroll
            for (int i = 0; i < 16; ++i) s2 += v[i] * v[i];
            s2 += __shfl_xor(s2, 1, 64);
            s2 += __shfl_xor(s2, 2, 64);
            s2 += __shfl_xor(s2, 4, 64);
            float nrm = sqrtf(s2);
            float rn = 1.0f / fmaxf(nrm, 1e-12f);
            union { unsigned char b[16]; uint4 u; } O;
#pragma unroll
            for (int i = 0; i < 16; ++i) O.b[i] = fp8e(v[i] * rn);
            *(uint4*)(pk + rl * 144 + q * 16) = O.u;
            if (q == 0 && gr < N) n1[gr] = nrm;
        }
        __syncthreads();
        {
            int boff = tid * 16;
            int r = boff >> 7;
            int inner = boff & 127;
            int gr = row0 + p * 32 + r;
            if (gr < N)
                *(uint4*)(xh1 + (size_t)gr * 128 + inner) =
                    *(const uint4*)(pk + r * 144 + inner);
        }
    }
}

// --- AGNN conv: fp8; 8 lanes/edge x 8 edges/round; 2-deep row pipe ---------
// lane: t = lane&7 (16 dims each), g = lane>>3 (edge slot).
// conv1: outf8+outn (normalized fp8 + norm); conv2: outbf (raw bf16 h3).
__global__ __launch_bounds__(256) void k_conv(const unsigned char* __restrict__ xh,
                                              const float* __restrict__ nrmt,
                                              const int* __restrict__ rp,
                                              const int* __restrict__ esrc, int N,
                                              const float* __restrict__ betap,
                                              unsigned char* __restrict__ outf8,
                                              float* __restrict__ outn,
                                              unsigned short* __restrict__ outbf) {
    int node = (blockIdx.x * blockDim.x + threadIdx.x) >> 6;
    if (node >= N) return;
    int lane = threadIdx.x & 63;
    int t = lane & 7, g = lane >> 3;
    float beta = betap ? *betap : 1.0f;

    uint4 hdu = *(const uint4*)&xh[(size_t)node * 128 + 16 * t];
    float hd[16];
    unpf16(hdu, hd);

    int e0 = rp[node], e1 = rp[node + 1];
    float acc[16];
#pragma unroll
    for (int j = 0; j < 16; ++j) acc[j] = 0.f;
    float ssum = 0.f;

    for (int cs = e0; cs < e1; cs += 64) {
        // batch: 64 edge indices coalesced, 64 norms in one gather
        int el = cs + lane;
        int sidx = esrc[(el < e1) ? el : e0];
        float nsl = nrmt[sidx];
        int R = e1 - cs;
        if (R > 64) R = 64;
        int nr = (R + 7) >> 3;           // 8 edges per round

        int sA = __shfl(sidx, g, 64);
        float nsA = __shfl(nsl, g, 64);
        uint4 rowA = *(const uint4*)&xh[(size_t)sA * 128 + 16 * t];

        for (int r = 0; r < nr; ++r) {
            const bool hasNext = (r + 1) < nr;  // wave-uniform
            uint4 rowB;
            float nsB = 0.f;
            if (hasNext) {
                int sB = __shfl(sidx, 8 * (r + 1) + g, 64);
                nsB = __shfl(nsl, 8 * (r + 1) + g, 64);
                rowB = *(const uint4*)&xh[(size_t)sB * 128 + 16 * t];
            }
            float v[16];
            unpf16(rowA, v);
            float p = 0.f;
#pragma unroll
            for (int j = 0; j < 16; ++j) p += v[j] * hd[j];
            p += __shfl_xor(p, 1, 64);
            p += __shfl_xor(p, 2, 64);
            p += __shfl_xor(p, 4, 64);
            int e = cs + 8 * r + g;
            float w = (e < e1) ? __expf(p * beta) : 0.f;
            float wn = w * nsA;
            ssum += w;
#pragma unroll
            for (int j = 0; j < 16; ++j) acc[j] += wn * v[j];
            if (hasNext) {
                rowA = rowB;
                nsA = nsB;
            }
        }
    }
#pragma unroll
    for (int j = 0; j < 16; ++j) {
        acc[j] += __shfl_xor(acc[j], 8, 64);
        acc[j] += __shfl_xor(acc[j], 16, 64);
        acc[j] += __shfl_xor(acc[j], 32, 64);
    }
    ssum += __shfl_xor(ssum, 8, 64);
    ssum += __shfl_xor(ssum, 16, 64);
    ssum += __shfl_xor(ssum, 32, 64);
    float r = 1.0f / ssum;

    if (outbf != nullptr) {
        // conv2: raw aggregated bf16 h3 (8 lanes x 32B)
        if (g == 0) {
            uint4 q0, q1;
            q0.x = pack2(acc[0] * r, acc[1] * r);
            q0.y = pack2(acc[2] * r, acc[3] * r);
            q0.z = pack2(acc[4] * r, acc[5] * r);
            q0.w = pack2(acc[6] * r, acc[7] * r);
            q1.x = pack2(acc[8] * r, acc[9] * r);
            q1.y = pack2(acc[10] * r, acc[11] * r);
            q1.z = pack2(acc[12] * r, acc[13] * r);
            q1.w = pack2(acc[14] * r, acc[15] * r);
            uint4* dst = (uint4*)&outbf[(size_t)node * 128 + 16 * t];
            dst[0] = q0;
            dst[1] = q1;
        }
    } else {
        // conv1: normalized fp8 x_hat + f32 norm (8 lanes x 16B)
        float o[16];
        float s2 = 0.f;
#pragma unroll
        for (int j = 0; j < 16; ++j) { o[j] = acc[j] * r; s2 += o[j] * o[j]; }
        s2 += __shfl_xor(s2, 1, 64);
        s2 += __shfl_xor(s2, 2, 64);
        s2 += __shfl_xor(s2, 4, 64);
        float nn = sqrtf(s2);
        float rn = 1.0f / fmaxf(nn, 1e-12f);
        if (g == 0) {
            union { unsigned char b[16]; uint4 u; } O;
#pragma unroll
            for (int j = 0; j < 16; ++j) O.b[j] = fp8e(o[j] * rn);
            *(uint4*)&outf8[(size_t)node * 128 + 16 * t] = O.u;
            if (t == 0) outn[node] = nn;
        }
    }
}

// --- GEMM2 (MFMA) + fused log_softmax --------------------------------------
#define G2_ASTRIDE 272
__global__ __launch_bounds__(256) void k_gemm2(const unsigned short* __restrict__ h,
                                               const unsigned short* __restrict__ W2t,
                                               const float* __restrict__ b2, int N,
                                               float* __restrict__ out) {
    __shared__ __align__(16) unsigned char As[128 * G2_ASTRIDE];
    __shared__ __align__(16) unsigned char Bs[64 * G2_ASTRIDE];
    const int tid = threadIdx.x;
    const int lane = tid & 63;
    const int lt = lane & 15, lg = lane >> 4;
    const int wid = tid >> 6;
    const int row0 = blockIdx.x * 128;

    {
        int arow = tid >> 1, ahalf = tid & 1;
        const uint4* src = (const uint4*)(h + (size_t)(row0 + arow) * 128 + ahalf * 64);
        unsigned char* ab = As + arow * G2_ASTRIDE + ahalf * 128;
#pragma unroll
        for (int i = 0; i < 8; ++i) ((uint4*)ab)[i] = src[i];
        int brow = tid >> 2, bq = tid & 3;
        const uint4* bs = (const uint4*)(W2t + (size_t)brow * 128 + bq * 32);
        unsigned char* bb = Bs + brow * G2_ASTRIDE + bq * 64;
#pragma unroll
        for (int i = 0; i < 4; ++i) ((uint4*)bb)[i] = bs[i];
    }
    __syncthreads();

    f32x4 acc[2][4];
#pragma unroll
    for (int i = 0; i < 2; ++i)
#pragma unroll
        for (int j = 0; j < 4; ++j) acc[i][j] = (f32x4){0.f, 0.f, 0.f, 0.f};

#pragma unroll
    for (int sub = 0; sub < 4; ++sub) {
        U16 af[2], bf[4];
#pragma unroll
        for (int mi = 0; mi < 2; ++mi)
            af[mi].u = *(const uint4*)(As + (wid * 32 + mi * 16 + lt) * G2_ASTRIDE + sub * 64 + lg * 16);
#pragma unroll
        for (int ni = 0; ni < 4; ++ni)
            bf[ni].u = *(const uint4*)(Bs + (ni * 16 + lt) * G2_ASTRIDE + sub * 64 + lg * 16);
#pragma unroll
        for (int mi = 0; mi < 2; ++mi)
#pragma unroll
            for (int ni = 0; ni < 4; ++ni)
                acc[mi][ni] = __builtin_amdgcn_mfma_f32_16x16x32_bf16(
                    af[mi].s, bf[ni].s, acc[mi][ni], 0, 0, 0);
    }

    float bias[4];
#pragma unroll
    for (int ni = 0; ni < 4; ++ni) bias[ni] = b2[ni * 16 + lt];

#pragma unroll
    for (int mi = 0; mi < 2; ++mi) {
#pragma unroll
        for (int reg = 0; reg < 4; ++reg) {
            int row = row0 + wid * 32 + mi * 16 + lg * 4 + reg;
            if (row < N) {
                float v[4];
#pragma unroll
                for (int ni = 0; ni < 4; ++ni) v[ni] = acc[mi][ni][reg] + bias[ni];
                float m = fmaxf(fmaxf(v[0], v[1]), fmaxf(v[2], v[3]));
                m = fmaxf(m, __shfl_xor(m, 1, 64));
                m = fmaxf(m, __shfl_xor(m, 2, 64));
                m = fmaxf(m, __shfl_xor(m, 4, 64));
                m = fmaxf(m, __shfl_xor(m, 8, 64));
                float s = __expf(v[0] - m) + __expf(v[1] - m) +
                          __expf(v[2] - m) + __expf(v[3] - m);
                s += __shfl_xor(s, 1, 64);
                s += __shfl_xor(s, 2, 64);
                s += __shfl_xor(s, 4, 64);
                s += __shfl_xor(s, 8, 64);
                float lg2 = logf(s);
#pragma unroll
                for (int ni = 0; ni < 4; ++ni)
                    out[(size_t)row * 64 + ni * 16 + lt] = v[ni] - m - lg2;
            }
        }
    }
}

// ---------------------------------------------------------------------------
extern "C" void kernel_launch(void* const* d_in, const int* in_sizes, int n_in,
                              void* d_out, int out_size, void* d_ws, size_t ws_size,
                              hipStream_t stream) {
    const float* x     = (const float*)d_in[0];
    const int*   ei    = (const int*)d_in[1];
    const float* W1    = (const float*)d_in[2];
    const float* b1    = (const float*)d_in[3];
    const float* beta2 = (const float*)d_in[4];
    const float* W2    = (const float*)d_in[5];
    const float* b2    = (const float*)d_in[6];
    float* out = (float*)d_out;

    const int N = in_sizes[0] / 512;
    const int E = in_sizes[1] / 2;
    const int Etot = E + N;

    char* ws = (char*)d_ws;
    size_t off = 0;
    auto alloc = [&](size_t bytes) -> void* {
        void* p = ws + off;
        off = (off + bytes + 511) & ~(size_t)511;
        return p;
    };
    unsigned char* t1  = (unsigned char*)alloc((size_t)N * 128);       // x_hat1 fp8
    unsigned char* t2  = (unsigned char*)alloc((size_t)N * 128);       // x_hat2 fp8
    unsigned short* h3 = (unsigned short*)alloc((size_t)N * 128 * 2);  // h3 bf16
    float* n1   = (float*)alloc((size_t)N * 4);
    float* n2   = (float*)alloc((size_t)N * 4);
    int* cnt    = (int*)alloc((size_t)N * 4);
    int* rp     = (int*)alloc((size_t)(N + 1) * 4);
    int* cursor = (int*)alloc((size_t)N * 4);
    int* bsum   = (int*)alloc(4096);
    unsigned short* W1t = (unsigned short*)alloc(512 * 128 * 2);
    unsigned short* W2t = (unsigned short*)alloc(128 * 64 * 2);
    int* s32    = (int*)alloc((size_t)E * 4);
    int* d32    = (int*)alloc((size_t)E * 4);
    int* esrc   = (int*)alloc((size_t)Etot * 4);
    (void)ws_size; (void)n_in; (void)out_size;

    (void)hipMemsetAsync(cnt, 0, (size_t)N * 4, stream);

    k_cvt<<<divup(E, 256), 256, 0, stream>>>(ei, E, s32, d32, cnt);
    int nb = divup(N, 1024);
    k_scan1<<<nb, 1024, 0, stream>>>(cnt, N, rp, bsum);
    k_scan2<<<1, 64, 0, stream>>>(bsum, nb);
    k_scan3<<<divup(N + 1, 256), 256, 0, stream>>>(rp, bsum, N, Etot, cursor);
    k_scatter<<<2048, 256, 0, stream>>>(s32, d32, E, N, cursor, esrc);

    k_cvtW1<<<divup(512 * 128, 256), 256, 0, stream>>>(W1, W1t);
    k_cvtW2<<<divup(128 * 64, 256), 256, 0, stream>>>(W2, W2t);

    k_gemm1<<<divup(N, 64), 256, 0, stream>>>(x, W1t, b1, N, t1, n1);
    k_conv<<<divup(N, 4), 256, 0, stream>>>(t1, n1, rp, esrc, N, nullptr, t2, n2, nullptr);
    k_conv<<<divup(N, 4), 256, 0, stream>>>(t2, n2, rp, esrc, N, beta2, nullptr, nullptr, h3);
    k_gemm2<<<divup(N, 128), 256, 0, stream>>>(h3, W2t, b2, N, out);
}

// Round 17
// 377.755 us; speedup vs baseline: 1.1296x; 1.1296x over previous
//
#include <hip/hip_runtime.h>
#include <hip/hip_fp8.h>
#include <math.h>

// ---------------------------------------------------------------------------
// AGNN round 17: revert conv to r15's verified 16 lanes/edge x 4 edges
// (8-lane geometry refuted twice: r6 +23us bf16, r16 +46us fp8 -> frozen).
// Keep r16's k_detect fold; merge k_cvtW1+k_cvtW2 into one launch.
// gemm1 = r15 4-slot loop-carried pipeline; fp8 tables (r14, error-free).
// ---------------------------------------------------------------------------

static inline int divup(int a, int b) { return (a + b - 1) / b; }

typedef __attribute__((ext_vector_type(8))) short short8;
typedef __attribute__((ext_vector_type(4))) float f32x4;
union U16 { uint4 u; short8 s; };

__device__ __forceinline__ unsigned bf16r(float f) {  // f32 -> bf16 bits, RNE
    unsigned u = __float_as_uint(f);
    return (u + 0x7FFFu + ((u >> 16) & 1u)) >> 16;
}
__device__ __forceinline__ unsigned pack2(float a, float b) {
    return bf16r(a) | (bf16r(b) << 16);
}
__device__ __forceinline__ float bflo(unsigned u) { return __uint_as_float(u << 16); }
__device__ __forceinline__ float bfhi(unsigned u) { return __uint_as_float(u & 0xFFFF0000u); }

__device__ __forceinline__ unsigned char fp8e(float f) {
    __hip_fp8_e4m3 q(f);
    return (unsigned char)q.__x;
}
__device__ __forceinline__ float fp8d(unsigned char b) {
    __hip_fp8_e4m3 q;
    q.__x = (__hip_fp8_storage_t)b;
    return (float)q;
}
__device__ __forceinline__ void unpf8(uint2 u, float* v) {
    const unsigned char* b = (const unsigned char*)&u;
#pragma unroll
    for (int i = 0; i < 8; ++i) v[i] = fp8d(b[i]);
}

// --- edge convert (+dtype autodetect per block, +histogram fold) -----------
__global__ __launch_bounds__(256) void k_cvt(const int* __restrict__ raw, int E,
                                             int* __restrict__ s32, int* __restrict__ d32,
                                             int* __restrict__ cnt) {
    __shared__ int sflag;
    int tid = threadIdx.x;
    if (tid < 64) {
        int v = raw[2 * tid + 1];
        unsigned long long b = __ballot(v != 0);
        if (tid == 0) sflag = (b == 0ULL) ? 1 : 0;  // 1 => int64 layout
    }
    __syncthreads();
    int flag = sflag;
    int i = blockIdx.x * blockDim.x + tid;
    if (i >= E) return;
    int s, d;
    if (flag) {
        s = raw[2 * (size_t)i];
        d = raw[2 * ((size_t)E + i)];
    } else {
        s = raw[i];
        d = raw[(size_t)E + i];
    }
    s32[i] = s;
    d32[i] = d;
    atomicAdd(&cnt[d], 1);
}

// --- CSR scan (cnt + 1 self-loop per node) ---------------------------------
__global__ __launch_bounds__(1024) void k_scan1(const int* __restrict__ cnt, int N,
                                                int* __restrict__ rp, int* __restrict__ bsum) {
    __shared__ int sm[1024];
    int t = threadIdx.x;
    int i = blockIdx.x * 1024 + t;
    int v = (i < N) ? cnt[i] + 1 : 0;  // +1: self-loop
    sm[t] = v;
    __syncthreads();
#pragma unroll
    for (int off = 1; off < 1024; off <<= 1) {
        int u = (t >= off) ? sm[t - off] : 0;
        __syncthreads();
        sm[t] += u;
        __syncthreads();
    }
    if (i < N) rp[i] = sm[t] - v;  // exclusive
    if (t == 1023) bsum[blockIdx.x] = sm[t];
}

__global__ __launch_bounds__(64) void k_scan2(int* __restrict__ bsum, int nb) {
    if (threadIdx.x == 0) {
        int run = 0;
        for (int i = 0; i < nb; ++i) { int v = bsum[i]; bsum[i] = run; run += v; }
    }
}

__global__ __launch_bounds__(256) void k_scan3(int* __restrict__ rp, const int* __restrict__ bsum,
                                               int N, int Etot, int* __restrict__ cursor) {
    int i = blockIdx.x * blockDim.x + threadIdx.x;
    if (i < N) {
        int v = rp[i] + bsum[i >> 10];
        rp[i] = v;
        cursor[i] = v;
    } else if (i == N) {
        rp[N] = Etot;
    }
}

// --- XCD-partitioned scatter -----------------------------------------------
__global__ __launch_bounds__(256) void k_scatter(const int* __restrict__ s32,
                                                 const int* __restrict__ d32, int E, int N,
                                                 int* __restrict__ cursor,
                                                 int* __restrict__ esrc) {
    int b = blockIdx.x;
    int xcd = b & 7;
    int nstripe = gridDim.x >> 3;
    int stripe = b >> 3;
    int lo = (int)(((long long)xcd * N) >> 3);
    int hi = (int)(((long long)(xcd + 1) * N) >> 3);
    int Etot = E + N;
    for (int e = stripe * 256 + threadIdx.x; e < Etot; e += nstripe * 256) {
        int d = (e < E) ? d32[e] : (e - E);
        if (d < lo || d >= hi) continue;
        int s = (e < E) ? s32[e] : d;
        int pos = atomicAdd(&cursor[d], 1);
        esrc[pos] = s;
    }
}

// --- weight preconvert (merged W1+W2) --------------------------------------
__global__ __launch_bounds__(256) void k_cvtW(const float* __restrict__ W1,
                                              const float* __restrict__ W2,
                                              unsigned short* __restrict__ W1t,
                                              unsigned short* __restrict__ W2t) {
    int i = blockIdx.x * 256 + threadIdx.x;
    if (i < 512 * 128) {
        int k = i >> 7, n = i & 127;
        W1t[n * 512 + k] = (unsigned short)bf16r(W1[i]);
    }
    if (i < 128 * 64) {
        int k = i >> 6, n = i & 63;
        W2t[n * 128 + k] = (unsigned short)bf16r(W2[i]);
    }
}

// --- GEMM1: x_hat1(fp8)/norm1 = normalize(relu(x @ W1 + b1)) ---------------
// 64-row tile, W-resident in 4 phases of 128k (32KB LDS),
// A-stream: loop-carried 4-slot modulo pipeline (r15, verified).
#define XSW(c, off) ((off) ^ (((c) & 7) << 4))
__global__ __launch_bounds__(256) void k_gemm1(const float* __restrict__ x,
                                               const unsigned short* __restrict__ W1t,
                                               const float* __restrict__ b1, int N,
                                               unsigned char* __restrict__ xh1,
                                               float* __restrict__ n1) {
    __shared__ __align__(16) unsigned char lds[32768];
    const int tid = threadIdx.x;
    const int lane = tid & 63;
    const int lt = lane & 15, lg = lane >> 4;
    const int w = tid >> 6;
    const int row0 = blockIdx.x * 64;

    int arow = row0 + w * 16 + lt;
    if (arow > N - 1) arow = N - 1;
    const float* xb = x + (size_t)arow * 512 + lg * 8;

    f32x4 acc[8];
#pragma unroll
    for (int j = 0; j < 8; ++j) acc[j] = (f32x4){0.f, 0.f, 0.f, 0.f};

    float4 buf[4][2];
#pragma unroll
    for (int j = 0; j < 4; ++j) {
        buf[j][0] = ((const float4*)(xb + j * 32))[0];
        buf[j][1] = ((const float4*)(xb + j * 32))[1];
    }

#pragma unroll 1
    for (int kt = 0; kt < 4; ++kt) {
        const int kb = kt * 128;
        __syncthreads();
        {
            int c = tid >> 1, h = tid & 1;
            const uint4* wp = (const uint4*)(W1t + c * 512 + kb + h * 64);
            unsigned char* base = lds + c * 256;
#pragma unroll
            for (int i = 0; i < 8; ++i)
                *(uint4*)(base + XSW(c, h * 128 + i * 16)) = wp[i];
        }
        __syncthreads();

        const bool more = kt < 3;
#pragma unroll
        for (int j = 0; j < 4; ++j) {
            U16 af;
            af.u.x = pack2(buf[j][0].x, buf[j][0].y);
            af.u.y = pack2(buf[j][0].z, buf[j][0].w);
            af.u.z = pack2(buf[j][1].x, buf[j][1].y);
            af.u.w = pack2(buf[j][1].z, buf[j][1].w);
            if (more) {
                const float* np = xb + (kt + 1) * 128 + j * 32;
                buf[j][0] = ((const float4*)np)[0];
                buf[j][1] = ((const float4*)np)[1];
            }
#pragma unroll
            for (int cf = 0; cf < 8; ++cf) {
                int col = cf * 16 + lt;
                U16 bf;
                bf.u = *(const uint4*)(lds + col * 256 + XSW(col, j * 64 + lg * 16));
                acc[cf] = __builtin_amdgcn_mfma_f32_16x16x32_bf16(
                    af.s, bf.s, acc[cf], 0, 0, 0);
            }
        }
    }

    float bias[8];
#pragma unroll
    for (int cf = 0; cf < 8; ++cf) bias[cf] = b1[cf * 16 + lt];
    float* sc = (float*)lds;              // 32 rows x 132 f32 = 16896B
    unsigned char* pk = lds + 16896;      // 32 rows x 144B = 4608B
#pragma unroll 1
    for (int p = 0; p < 2; ++p) {
        __syncthreads();
        if ((w >> 1) == p) {
#pragma unroll
            for (int reg = 0; reg < 4; ++reg) {
                int rl = (w & 1) * 16 + lg * 4 + reg;
#pragma unroll
                for (int cf = 0; cf < 8; ++cf)
                    sc[rl * 132 + cf * 16 + lt] =
                        fmaxf(acc[cf][reg] + bias[cf], 0.f);
            }
        }
        __syncthreads();
        {
            int rl = tid >> 3, q = tid & 7;
            int gr = row0 + p * 32 + rl;
            const float* rowp = sc + rl * 132 + q * 16;
            float v[16];
#pragma unroll
            for (int i = 0; i < 4; ++i) {
                float4 f = ((const float4*)rowp)[i];
                v[4 * i] = f.x; v[4 * i + 1] = f.y; v[4 * i + 2] = f.z; v[4 * i + 3] = f.w;
            }
            float s2 = 0.f;
#pragma unroll
            for (int i = 0; i < 16; ++i) s2 += v[i] * v[i];
            s2 += __shfl_xor(s2, 1, 64);
            s2 += __shfl_xor(s2, 2, 64);
            s2 += __shfl_xor(s2, 4, 64);
            float nrm = sqrtf(s2);
            float rn = 1.0f / fmaxf(nrm, 1e-12f);
            union { unsigned char b[16]; uint4 u; } O;
#pragma unroll
            for (int i = 0; i < 16; ++i) O.b[i] = fp8e(v[i] * rn);
            *(uint4*)(pk + rl * 144 + q * 16) = O.u;
            if (q == 0 && gr < N) n1[gr] = nrm;
        }
        __syncthreads();
        {
            int boff = tid * 16;
            int r = boff >> 7;
            int inner = boff & 127;
            int gr = row0 + p * 32 + r;
            if (gr < N)
                *(uint4*)(xh1 + (size_t)gr * 128 + inner) =
                    *(const uint4*)(pk + r * 144 + inner);
        }
    }
}

// --- AGNN conv: fp8; 16 lanes/edge x 4 edges; chunked idx batch; 2-deep ----
__global__ __launch_bounds__(256) void k_conv(const unsigned char* __restrict__ xh,
                                              const float* __restrict__ nrmt,
                                              const int* __restrict__ rp,
                                              const int* __restrict__ esrc, int N,
                                              const float* __restrict__ betap,
                                              unsigned char* __restrict__ outf8,
                                              float* __restrict__ outn,
                                              unsigned short* __restrict__ outbf) {
    int node = (blockIdx.x * blockDim.x + threadIdx.x) >> 6;
    if (node >= N) return;
    int lane = threadIdx.x & 63;
    int t = lane & 15, g = lane >> 4;
    float beta = betap ? *betap : 1.0f;

    uint2 hdu = *(const uint2*)&xh[(size_t)node * 128 + 8 * t];
    float hd[8];
    unpf8(hdu, hd);

    int e0 = rp[node], e1 = rp[node + 1];
    float acc[8] = {0.f, 0.f, 0.f, 0.f, 0.f, 0.f, 0.f, 0.f};
    float ssum = 0.f;

    for (int cs = e0; cs < e1; cs += 64) {
        int el = cs + lane;
        int sidx = esrc[(el < e1) ? el : e0];
        float nsl = nrmt[sidx];
        int R = e1 - cs;
        if (R > 64) R = 64;
        int nr = (R + 3) >> 2;

        int sA = __shfl(sidx, g, 64);
        float nsA = __shfl(nsl, g, 64);
        uint2 rowA = *(const uint2*)&xh[(size_t)sA * 128 + 8 * t];

        for (int r = 0; r < nr; ++r) {
            const bool hasNext = (r + 1) < nr;
            uint2 rowB;
            float nsB = 0.f;
            if (hasNext) {
                int sB = __shfl(sidx, 4 * (r + 1) + g, 64);
                nsB = __shfl(nsl, 4 * (r + 1) + g, 64);
                rowB = *(const uint2*)&xh[(size_t)sB * 128 + 8 * t];
            }
            float v[8];
            unpf8(rowA, v);
            float p = 0.f;
#pragma unroll
            for (int j = 0; j < 8; ++j) p += v[j] * hd[j];
            p += __shfl_xor(p, 1, 64);
            p += __shfl_xor(p, 2, 64);
            p += __shfl_xor(p, 4, 64);
            p += __shfl_xor(p, 8, 64);
            int e = cs + 4 * r + g;
            float w = (e < e1) ? __expf(p * beta) : 0.f;
            float wn = w * nsA;
            ssum += w;
#pragma unroll
            for (int j = 0; j < 8; ++j) acc[j] += wn * v[j];
            if (hasNext) {
                rowA = rowB;
                nsA = nsB;
            }
        }
    }
#pragma unroll
    for (int j = 0; j < 8; ++j) {
        acc[j] += __shfl_xor(acc[j], 16, 64);
        acc[j] += __shfl_xor(acc[j], 32, 64);
    }
    ssum += __shfl_xor(ssum, 16, 64);
    ssum += __shfl_xor(ssum, 32, 64);
    float r = 1.0f / ssum;

    if (outbf != nullptr) {
        if (g == 0) {
            uint4 q;
            q.x = pack2(acc[0] * r, acc[1] * r);
            q.y = pack2(acc[2] * r, acc[3] * r);
            q.z = pack2(acc[4] * r, acc[5] * r);
            q.w = pack2(acc[6] * r, acc[7] * r);
            *(uint4*)&outbf[(size_t)node * 128 + 8 * t] = q;
        }
    } else {
        float o[8];
        float s2 = 0.f;
#pragma unroll
        for (int j = 0; j < 8; ++j) { o[j] = acc[j] * r; s2 += o[j] * o[j]; }
        s2 += __shfl_xor(s2, 1, 64);
        s2 += __shfl_xor(s2, 2, 64);
        s2 += __shfl_xor(s2, 4, 64);
        s2 += __shfl_xor(s2, 8, 64);
        float nn = sqrtf(s2);
        float rn = 1.0f / fmaxf(nn, 1e-12f);
        if (g == 0) {
            union { unsigned char b[8]; uint2 u; } O;
#pragma unroll
            for (int j = 0; j < 8; ++j) O.b[j] = fp8e(o[j] * rn);
            *(uint2*)&outf8[(size_t)node * 128 + 8 * t] = O.u;
            if (t == 0) outn[node] = nn;
        }
    }
}

// --- GEMM2 (MFMA) + fused log_softmax --------------------------------------
#define G2_ASTRIDE 272
__global__ __launch_bounds__(256) void k_gemm2(const unsigned short* __restrict__ h,
                                               const unsigned short* __restrict__ W2t,
                                               const float* __restrict__ b2, int N,
                                               float* __restrict__ out) {
    __shared__ __align__(16) unsigned char As[128 * G2_ASTRIDE];
    __shared__ __align__(16) unsigned char Bs[64 * G2_ASTRIDE];
    const int tid = threadIdx.x;
    const int lane = tid & 63;
    const int lt = lane & 15, lg = lane >> 4;
    const int wid = tid >> 6;
    const int row0 = blockIdx.x * 128;

    {
        int arow = tid >> 1, ahalf = tid & 1;
        const uint4* src = (const uint4*)(h + (size_t)(row0 + arow) * 128 + ahalf * 64);
        unsigned char* ab = As + arow * G2_ASTRIDE + ahalf * 128;
#pragma unroll
        for (int i = 0; i < 8; ++i) ((uint4*)ab)[i] = src[i];
        int brow = tid >> 2, bq = tid & 3;
        const uint4* bs = (const uint4*)(W2t + (size_t)brow * 128 + bq * 32);
        unsigned char* bb = Bs + brow * G2_ASTRIDE + bq * 64;
#pragma unroll
        for (int i = 0; i < 4; ++i) ((uint4*)bb)[i] = bs[i];
    }
    __syncthreads();

    f32x4 acc[2][4];
#pragma unroll
    for (int i = 0; i < 2; ++i)
#pragma unroll
        for (int j = 0; j < 4; ++j) acc[i][j] = (f32x4){0.f, 0.f, 0.f, 0.f};

#pragma unroll
    for (int sub = 0; sub < 4; ++sub) {
        U16 af[2], bf[4];
#pragma unroll
        for (int mi = 0; mi < 2; ++mi)
            af[mi].u = *(const uint4*)(As + (wid * 32 + mi * 16 + lt) * G2_ASTRIDE + sub * 64 + lg * 16);
#pragma unroll
        for (int ni = 0; ni < 4; ++ni)
            bf[ni].u = *(const uint4*)(Bs + (ni * 16 + lt) * G2_ASTRIDE + sub * 64 + lg * 16);
#pragma unroll
        for (int mi = 0; mi < 2; ++mi)
#pragma unroll
            for (int ni = 0; ni < 4; ++ni)
                acc[mi][ni] = __builtin_amdgcn_mfma_f32_16x16x32_bf16(
                    af[mi].s, bf[ni].s, acc[mi][ni], 0, 0, 0);
    }

    float bias[4];
#pragma unroll
    for (int ni = 0; ni < 4; ++ni) bias[ni] = b2[ni * 16 + lt];

#pragma unroll
    for (int mi = 0; mi < 2; ++mi) {
#pragma unroll
        for (int reg = 0; reg < 4; ++reg) {
            int row = row0 + wid * 32 + mi * 16 + lg * 4 + reg;
            if (row < N) {
                float v[4];
#pragma unroll
                for (int ni = 0; ni < 4; ++ni) v[ni] = acc[mi][ni][reg] + bias[ni];
                float m = fmaxf(fmaxf(v[0], v[1]), fmaxf(v[2], v[3]));
                m = fmaxf(m, __shfl_xor(m, 1, 64));
                m = fmaxf(m, __shfl_xor(m, 2, 64));
                m = fmaxf(m, __shfl_xor(m, 4, 64));
                m = fmaxf(m, __shfl_xor(m, 8, 64));
                float s = __expf(v[0] - m) + __expf(v[1] - m) +
                          __expf(v[2] - m) + __expf(v[3] - m);
                s += __shfl_xor(s, 1, 64);
                s += __shfl_xor(s, 2, 64);
                s += __shfl_xor(s, 4, 64);
                s += __shfl_xor(s, 8, 64);
                float lg2 = logf(s);
#pragma unroll
                for (int ni = 0; ni < 4; ++ni)
                    out[(size_t)row * 64 + ni * 16 + lt] = v[ni] - m - lg2;
            }
        }
    }
}

// ---------------------------------------------------------------------------
extern "C" void kernel_launch(void* const* d_in, const int* in_sizes, int n_in,
                              void* d_out, int out_size, void* d_ws, size_t ws_size,
                              hipStream_t stream) {
    const float* x     = (const float*)d_in[0];
    const int*   ei    = (const int*)d_in[1];
    const float* W1    = (const float*)d_in[2];
    const float* b1    = (const float*)d_in[3];
    const float* beta2 = (const float*)d_in[4];
    const float* W2    = (const float*)d_in[5];
    const float* b2    = (const float*)d_in[6];
    float* out = (float*)d_out;

    const int N = in_sizes[0] / 512;
    const int E = in_sizes[1] / 2;
    const int Etot = E + N;

    char* ws = (char*)d_ws;
    size_t off = 0;
    auto alloc = [&](size_t bytes) -> void* {
        void* p = ws + off;
        off = (off + bytes + 511) & ~(size_t)511;
        return p;
    };
    unsigned char* t1  = (unsigned char*)alloc((size_t)N * 128);       // x_hat1 fp8
    unsigned char* t2  = (unsigned char*)alloc((size_t)N * 128);       // x_hat2 fp8
    unsigned short* h3 = (unsigned short*)alloc((size_t)N * 128 * 2);  // h3 bf16
    float* n1   = (float*)alloc((size_t)N * 4);
    float* n2   = (float*)alloc((size_t)N * 4);
    int* cnt    = (int*)alloc((size_t)N * 4);
    int* rp     = (int*)alloc((size_t)(N + 1) * 4);
    int* cursor = (int*)alloc((size_t)N * 4);
    int* bsum   = (int*)alloc(4096);
    unsigned short* W1t = (unsigned short*)alloc(512 * 128 * 2);
    unsigned short* W2t = (unsigned short*)alloc(128 * 64 * 2);
    int* s32    = (int*)alloc((size_t)E * 4);
    int* d32    = (int*)alloc((size_t)E * 4);
    int* esrc   = (int*)alloc((size_t)Etot * 4);
    (void)ws_size; (void)n_in; (void)out_size;

    (void)hipMemsetAsync(cnt, 0, (size_t)N * 4, stream);

    k_cvt<<<divup(E, 256), 256, 0, stream>>>(ei, E, s32, d32, cnt);
    int nb = divup(N, 1024);
    k_scan1<<<nb, 1024, 0, stream>>>(cnt, N, rp, bsum);
    k_scan2<<<1, 64, 0, stream>>>(bsum, nb);
    k_scan3<<<divup(N + 1, 256), 256, 0, stream>>>(rp, bsum, N, Etot, cursor);
    k_scatter<<<2048, 256, 0, stream>>>(s32, d32, E, N, cursor, esrc);

    k_cvtW<<<divup(512 * 128, 256), 256, 0, stream>>>(W1, W2, W1t, W2t);

    k_gemm1<<<divup(N, 64), 256, 0, stream>>>(x, W1t, b1, N, t1, n1);
    k_conv<<<divup(N, 4), 256, 0, stream>>>(t1, n1, rp, esrc, N, nullptr, t2, n2, nullptr);
    k_conv<<<divup(N, 4), 256, 0, stream>>>(t2, n2, rp, esrc, N, beta2, nullptr, nullptr, h3);
    k_gemm2<<<divup(N, 128), 256, 0, stream>>>(h3, W2t, b2, N, out);
}

// Round 18
// 376.265 us; speedup vs baseline: 1.1340x; 1.0040x over previous
//
#include <hip/hip_runtime.h>
#include <hip/hip_fp8.h>
#include <math.h>

// ---------------------------------------------------------------------------
// AGNN round 18: remove the edge-list materialization (s32/d32). k_hist and
// k_scatter read raw edge_index directly with per-block ballot autodetect
// (int64 vs int32 layout) -> one less launch, -13.6MB stores, -13.6MB reads.
// All compute kernels byte-identical to r17 (verified best, 377.8us):
// gemm1 = r15 4-slot loop-carried pipeline; conv = 16x4 fp8 chunked 2-deep;
// gemm2 = MFMA + fused log_softmax; fp8 tables (error-free vs bf16).
// ---------------------------------------------------------------------------

static inline int divup(int a, int b) { return (a + b - 1) / b; }

typedef __attribute__((ext_vector_type(8))) short short8;
typedef __attribute__((ext_vector_type(4))) float f32x4;
union U16 { uint4 u; short8 s; };

__device__ __forceinline__ unsigned bf16r(float f) {  // f32 -> bf16 bits, RNE
    unsigned u = __float_as_uint(f);
    return (u + 0x7FFFu + ((u >> 16) & 1u)) >> 16;
}
__device__ __forceinline__ unsigned pack2(float a, float b) {
    return bf16r(a) | (bf16r(b) << 16);
}
__device__ __forceinline__ float bflo(unsigned u) { return __uint_as_float(u << 16); }
__device__ __forceinline__ float bfhi(unsigned u) { return __uint_as_float(u & 0xFFFF0000u); }

__device__ __forceinline__ unsigned char fp8e(float f) {
    __hip_fp8_e4m3 q(f);
    return (unsigned char)q.__x;
}
__device__ __forceinline__ float fp8d(unsigned char b) {
    __hip_fp8_e4m3 q;
    q.__x = (__hip_fp8_storage_t)b;
    return (float)q;
}
__device__ __forceinline__ void unpf8(uint2 u, float* v) {
    const unsigned char* b = (const unsigned char*)&u;
#pragma unroll
    for (int i = 0; i < 8; ++i) v[i] = fp8d(b[i]);
}

// per-block int64/int32 layout autodetect (deterministic across blocks)
__device__ __forceinline__ int edge_flag(const int* raw) {
    __shared__ int sflag;
    if (threadIdx.x < 64) {
        int v = raw[2 * threadIdx.x + 1];
        unsigned long long b = __ballot(v != 0);
        if (threadIdx.x == 0) sflag = (b == 0ULL) ? 1 : 0;  // 1 => int64
    }
    __syncthreads();
    return sflag;
}
__device__ __forceinline__ int edge_src(const int* raw, int E, int flag, int i) {
    return flag ? raw[2 * (size_t)i] : raw[i];
}
__device__ __forceinline__ int edge_dst(const int* raw, int E, int flag, int i) {
    return flag ? raw[2 * ((size_t)E + i)] : raw[(size_t)E + i];
}

// --- histogram straight off raw edge_index ---------------------------------
__global__ __launch_bounds__(256) void k_hist(const int* __restrict__ raw, int E,
                                              int* __restrict__ cnt) {
    int flag = edge_flag(raw);
    int i = blockIdx.x * blockDim.x + threadIdx.x;
    if (i >= E) return;
    atomicAdd(&cnt[edge_dst(raw, E, flag, i)], 1);
}

// --- CSR scan (cnt + 1 self-loop per node) ---------------------------------
__global__ __launch_bounds__(1024) void k_scan1(const int* __restrict__ cnt, int N,
                                                int* __restrict__ rp, int* __restrict__ bsum) {
    __shared__ int sm[1024];
    int t = threadIdx.x;
    int i = blockIdx.x * 1024 + t;
    int v = (i < N) ? cnt[i] + 1 : 0;  // +1: self-loop
    sm[t] = v;
    __syncthreads();
#pragma unroll
    for (int off = 1; off < 1024; off <<= 1) {
        int u = (t >= off) ? sm[t - off] : 0;
        __syncthreads();
        sm[t] += u;
        __syncthreads();
    }
    if (i < N) rp[i] = sm[t] - v;  // exclusive
    if (t == 1023) bsum[blockIdx.x] = sm[t];
}

__global__ __launch_bounds__(64) void k_scan2(int* __restrict__ bsum, int nb) {
    if (threadIdx.x == 0) {
        int run = 0;
        for (int i = 0; i < nb; ++i) { int v = bsum[i]; bsum[i] = run; run += v; }
    }
}

__global__ __launch_bounds__(256) void k_scan3(int* __restrict__ rp, const int* __restrict__ bsum,
                                               int N, int Etot, int* __restrict__ cursor) {
    int i = blockIdx.x * blockDim.x + threadIdx.x;
    if (i < N) {
        int v = rp[i] + bsum[i >> 10];
        rp[i] = v;
        cursor[i] = v;
    } else if (i == N) {
        rp[N] = Etot;
    }
}

// --- XCD-partitioned scatter straight off raw edge_index -------------------
__global__ __launch_bounds__(256) void k_scatter(const int* __restrict__ raw, int E, int N,
                                                 int* __restrict__ cursor,
                                                 int* __restrict__ esrc) {
    int flag = edge_flag(raw);
    int b = blockIdx.x;
    int xcd = b & 7;
    int nstripe = gridDim.x >> 3;
    int stripe = b >> 3;
    int lo = (int)(((long long)xcd * N) >> 3);
    int hi = (int)(((long long)(xcd + 1) * N) >> 3);
    int Etot = E + N;
    for (int e = stripe * 256 + threadIdx.x; e < Etot; e += nstripe * 256) {
        int d = (e < E) ? edge_dst(raw, E, flag, e) : (e - E);
        if (d < lo || d >= hi) continue;
        int s = (e < E) ? edge_src(raw, E, flag, e) : d;
        int pos = atomicAdd(&cursor[d], 1);
        esrc[pos] = s;
    }
}

// --- weight preconvert (merged W1+W2) --------------------------------------
__global__ __launch_bounds__(256) void k_cvtW(const float* __restrict__ W1,
                                              const float* __restrict__ W2,
                                              unsigned short* __restrict__ W1t,
                                              unsigned short* __restrict__ W2t) {
    int i = blockIdx.x * 256 + threadIdx.x;
    if (i < 512 * 128) {
        int k = i >> 7, n = i & 127;
        W1t[n * 512 + k] = (unsigned short)bf16r(W1[i]);
    }
    if (i < 128 * 64) {
        int k = i >> 6, n = i & 63;
        W2t[n * 128 + k] = (unsigned short)bf16r(W2[i]);
    }
}

// --- GEMM1: x_hat1(fp8)/norm1 = normalize(relu(x @ W1 + b1)) ---------------
// 64-row tile, W-resident in 4 phases of 128k (32KB LDS),
// A-stream: loop-carried 4-slot modulo pipeline (r15, verified).
#define XSW(c, off) ((off) ^ (((c) & 7) << 4))
__global__ __launch_bounds__(256) void k_gemm1(const float* __restrict__ x,
                                               const unsigned short* __restrict__ W1t,
                                               const float* __restrict__ b1, int N,
                                               unsigned char* __restrict__ xh1,
                                               float* __restrict__ n1) {
    __shared__ __align__(16) unsigned char lds[32768];
    const int tid = threadIdx.x;
    const int lane = tid & 63;
    const int lt = lane & 15, lg = lane >> 4;
    const int w = tid >> 6;
    const int row0 = blockIdx.x * 64;

    int arow = row0 + w * 16 + lt;
    if (arow > N - 1) arow = N - 1;
    const float* xb = x + (size_t)arow * 512 + lg * 8;

    f32x4 acc[8];
#pragma unroll
    for (int j = 0; j < 8; ++j) acc[j] = (f32x4){0.f, 0.f, 0.f, 0.f};

    float4 buf[4][2];
#pragma unroll
    for (int j = 0; j < 4; ++j) {
        buf[j][0] = ((const float4*)(xb + j * 32))[0];
        buf[j][1] = ((const float4*)(xb + j * 32))[1];
    }

#pragma unroll 1
    for (int kt = 0; kt < 4; ++kt) {
        const int kb = kt * 128;
        __syncthreads();
        {
            int c = tid >> 1, h = tid & 1;
            const uint4* wp = (const uint4*)(W1t + c * 512 + kb + h * 64);
            unsigned char* base = lds + c * 256;
#pragma unroll
            for (int i = 0; i < 8; ++i)
                *(uint4*)(base + XSW(c, h * 128 + i * 16)) = wp[i];
        }
        __syncthreads();

        const bool more = kt < 3;
#pragma unroll
        for (int j = 0; j < 4; ++j) {
            U16 af;
            af.u.x = pack2(buf[j][0].x, buf[j][0].y);
            af.u.y = pack2(buf[j][0].z, buf[j][0].w);
            af.u.z = pack2(buf[j][1].x, buf[j][1].y);
            af.u.w = pack2(buf[j][1].z, buf[j][1].w);
            if (more) {
                const float* np = xb + (kt + 1) * 128 + j * 32;
                buf[j][0] = ((const float4*)np)[0];
                buf[j][1] = ((const float4*)np)[1];
            }
#pragma unroll
            for (int cf = 0; cf < 8; ++cf) {
                int col = cf * 16 + lt;
                U16 bf;
                bf.u = *(const uint4*)(lds + col * 256 + XSW(col, j * 64 + lg * 16));
                acc[cf] = __builtin_amdgcn_mfma_f32_16x16x32_bf16(
                    af.s, bf.s, acc[cf], 0, 0, 0);
            }
        }
    }

    float bias[8];
#pragma unroll
    for (int cf = 0; cf < 8; ++cf) bias[cf] = b1[cf * 16 + lt];
    float* sc = (float*)lds;              // 32 rows x 132 f32 = 16896B
    unsigned char* pk = lds + 16896;      // 32 rows x 144B = 4608B
#pragma unroll 1
    for (int p = 0; p < 2; ++p) {
        __syncthreads();
        if ((w >> 1) == p) {
#pragma unroll
            for (int reg = 0; reg < 4; ++reg) {
                int rl = (w & 1) * 16 + lg * 4 + reg;
#pragma unroll
                for (int cf = 0; cf < 8; ++cf)
                    sc[rl * 132 + cf * 16 + lt] =
                        fmaxf(acc[cf][reg] + bias[cf], 0.f);
            }
        }
        __syncthreads();
        {
            int rl = tid >> 3, q = tid & 7;
            int gr = row0 + p * 32 + rl;
            const float* rowp = sc + rl * 132 + q * 16;
            float v[16];
#pragma unroll
            for (int i = 0; i < 4; ++i) {
                float4 f = ((const float4*)rowp)[i];
                v[4 * i] = f.x; v[4 * i + 1] = f.y; v[4 * i + 2] = f.z; v[4 * i + 3] = f.w;
            }
            float s2 = 0.f;
#pragma unroll
            for (int i = 0; i < 16; ++i) s2 += v[i] * v[i];
            s2 += __shfl_xor(s2, 1, 64);
            s2 += __shfl_xor(s2, 2, 64);
            s2 += __shfl_xor(s2, 4, 64);
            float nrm = sqrtf(s2);
            float rn = 1.0f / fmaxf(nrm, 1e-12f);
            union { unsigned char b[16]; uint4 u; } O;
#pragma unroll
            for (int i = 0; i < 16; ++i) O.b[i] = fp8e(v[i] * rn);
            *(uint4*)(pk + rl * 144 + q * 16) = O.u;
            if (q == 0 && gr < N) n1[gr] = nrm;
        }
        __syncthreads();
        {
            int boff = tid * 16;
            int r = boff >> 7;
            int inner = boff & 127;
            int gr = row0 + p * 32 + r;
            if (gr < N)
                *(uint4*)(xh1 + (size_t)gr * 128 + inner) =
                    *(const uint4*)(pk + r * 144 + inner);
        }
    }
}

// --- AGNN conv: fp8; 16 lanes/edge x 4 edges; chunked idx batch; 2-deep ----
__global__ __launch_bounds__(256) void k_conv(const unsigned char* __restrict__ xh,
                                              const float* __restrict__ nrmt,
                                              const int* __restrict__ rp,
                                              const int* __restrict__ esrc, int N,
                                              const float* __restrict__ betap,
                                              unsigned char* __restrict__ outf8,
                                              float* __restrict__ outn,
                                              unsigned short* __restrict__ outbf) {
    int node = (blockIdx.x * blockDim.x + threadIdx.x) >> 6;
    if (node >= N) return;
    int lane = threadIdx.x & 63;
    int t = lane & 15, g = lane >> 4;
    float beta = betap ? *betap : 1.0f;

    uint2 hdu = *(const uint2*)&xh[(size_t)node * 128 + 8 * t];
    float hd[8];
    unpf8(hdu, hd);

    int e0 = rp[node], e1 = rp[node + 1];
    float acc[8] = {0.f, 0.f, 0.f, 0.f, 0.f, 0.f, 0.f, 0.f};
    float ssum = 0.f;

    for (int cs = e0; cs < e1; cs += 64) {
        int el = cs + lane;
        int sidx = esrc[(el < e1) ? el : e0];
        float nsl = nrmt[sidx];
        int R = e1 - cs;
        if (R > 64) R = 64;
        int nr = (R + 3) >> 2;

        int sA = __shfl(sidx, g, 64);
        float nsA = __shfl(nsl, g, 64);
        uint2 rowA = *(const uint2*)&xh[(size_t)sA * 128 + 8 * t];

        for (int r = 0; r < nr; ++r) {
            const bool hasNext = (r + 1) < nr;
            uint2 rowB;
            float nsB = 0.f;
            if (hasNext) {
                int sB = __shfl(sidx, 4 * (r + 1) + g, 64);
                nsB = __shfl(nsl, 4 * (r + 1) + g, 64);
                rowB = *(const uint2*)&xh[(size_t)sB * 128 + 8 * t];
            }
            float v[8];
            unpf8(rowA, v);
            float p = 0.f;
#pragma unroll
            for (int j = 0; j < 8; ++j) p += v[j] * hd[j];
            p += __shfl_xor(p, 1, 64);
            p += __shfl_xor(p, 2, 64);
            p += __shfl_xor(p, 4, 64);
            p += __shfl_xor(p, 8, 64);
            int e = cs + 4 * r + g;
            float w = (e < e1) ? __expf(p * beta) : 0.f;
            float wn = w * nsA;
            ssum += w;
#pragma unroll
            for (int j = 0; j < 8; ++j) acc[j] += wn * v[j];
            if (hasNext) {
                rowA = rowB;
                nsA = nsB;
            }
        }
    }
#pragma unroll
    for (int j = 0; j < 8; ++j) {
        acc[j] += __shfl_xor(acc[j], 16, 64);
        acc[j] += __shfl_xor(acc[j], 32, 64);
    }
    ssum += __shfl_xor(ssum, 16, 64);
    ssum += __shfl_xor(ssum, 32, 64);
    float r = 1.0f / ssum;

    if (outbf != nullptr) {
        if (g == 0) {
            uint4 q;
            q.x = pack2(acc[0] * r, acc[1] * r);
            q.y = pack2(acc[2] * r, acc[3] * r);
            q.z = pack2(acc[4] * r, acc[5] * r);
            q.w = pack2(acc[6] * r, acc[7] * r);
            *(uint4*)&outbf[(size_t)node * 128 + 8 * t] = q;
        }
    } else {
        float o[8];
        float s2 = 0.f;
#pragma unroll
        for (int j = 0; j < 8; ++j) { o[j] = acc[j] * r; s2 += o[j] * o[j]; }
        s2 += __shfl_xor(s2, 1, 64);
        s2 += __shfl_xor(s2, 2, 64);
        s2 += __shfl_xor(s2, 4, 64);
        s2 += __shfl_xor(s2, 8, 64);
        float nn = sqrtf(s2);
        float rn = 1.0f / fmaxf(nn, 1e-12f);
        if (g == 0) {
            union { unsigned char b[8]; uint2 u; } O;
#pragma unroll
            for (int j = 0; j < 8; ++j) O.b[j] = fp8e(o[j] * rn);
            *(uint2*)&outf8[(size_t)node * 128 + 8 * t] = O.u;
            if (t == 0) outn[node] = nn;
        }
    }
}

// --- GEMM2 (MFMA) + fused log_softmax --------------------------------------
#define G2_ASTRIDE 272
__global__ __launch_bounds__(256) void k_gemm2(const unsigned short* __restrict__ h,
                                               const unsigned short* __restrict__ W2t,
                                               const float* __restrict__ b2, int N,
                                               float* __restrict__ out) {
    __shared__ __align__(16) unsigned char As[128 * G2_ASTRIDE];
    __shared__ __align__(16) unsigned char Bs[64 * G2_ASTRIDE];
    const int tid = threadIdx.x;
    const int lane = tid & 63;
    const int lt = lane & 15, lg = lane >> 4;
    const int wid = tid >> 6;
    const int row0 = blockIdx.x * 128;

    {
        int arow = tid >> 1, ahalf = tid & 1;
        const uint4* src = (const uint4*)(h + (size_t)(row0 + arow) * 128 + ahalf * 64);
        unsigned char* ab = As + arow * G2_ASTRIDE + ahalf * 128;
#pragma unroll
        for (int i = 0; i < 8; ++i) ((uint4*)ab)[i] = src[i];
        int brow = tid >> 2, bq = tid & 3;
        const uint4* bs = (const uint4*)(W2t + (size_t)brow * 128 + bq * 32);
        unsigned char* bb = Bs + brow * G2_ASTRIDE + bq * 64;
#pragma unroll
        for (int i = 0; i < 4; ++i) ((uint4*)bb)[i] = bs[i];
    }
    __syncthreads();

    f32x4 acc[2][4];
#pragma unroll
    for (int i = 0; i < 2; ++i)
#pragma unroll
        for (int j = 0; j < 4; ++j) acc[i][j] = (f32x4){0.f, 0.f, 0.f, 0.f};

#pragma unroll
    for (int sub = 0; sub < 4; ++sub) {
        U16 af[2], bf[4];
#pragma unroll
        for (int mi = 0; mi < 2; ++mi)
            af[mi].u = *(const uint4*)(As + (wid * 32 + mi * 16 + lt) * G2_ASTRIDE + sub * 64 + lg * 16);
#pragma unroll
        for (int ni = 0; ni < 4; ++ni)
            bf[ni].u = *(const uint4*)(Bs + (ni * 16 + lt) * G2_ASTRIDE + sub * 64 + lg * 16);
#pragma unroll
        for (int mi = 0; mi < 2; ++mi)
#pragma unroll
            for (int ni = 0; ni < 4; ++ni)
                acc[mi][ni] = __builtin_amdgcn_mfma_f32_16x16x32_bf16(
                    af[mi].s, bf[ni].s, acc[mi][ni], 0, 0, 0);
    }

    float bias[4];
#pragma unroll
    for (int ni = 0; ni < 4; ++ni) bias[ni] = b2[ni * 16 + lt];

#pragma unroll
    for (int mi = 0; mi < 2; ++mi) {
#pragma unroll
        for (int reg = 0; reg < 4; ++reg) {
            int row = row0 + wid * 32 + mi * 16 + lg * 4 + reg;
            if (row < N) {
                float v[4];
#pragma unroll
                for (int ni = 0; ni < 4; ++ni) v[ni] = acc[mi][ni][reg] + bias[ni];
                float m = fmaxf(fmaxf(v[0], v[1]), fmaxf(v[2], v[3]));
                m = fmaxf(m, __shfl_xor(m, 1, 64));
                m = fmaxf(m, __shfl_xor(m, 2, 64));
                m = fmaxf(m, __shfl_xor(m, 4, 64));
                m = fmaxf(m, __shfl_xor(m, 8, 64));
                float s = __expf(v[0] - m) + __expf(v[1] - m) +
                          __expf(v[2] - m) + __expf(v[3] - m);
                s += __shfl_xor(s, 1, 64);
                s += __shfl_xor(s, 2, 64);
                s += __shfl_xor(s, 4, 64);
                s += __shfl_xor(s, 8, 64);
                float lg2 = logf(s);
#pragma unroll
                for (int ni = 0; ni < 4; ++ni)
                    out[(size_t)row * 64 + ni * 16 + lt] = v[ni] - m - lg2;
            }
        }
    }
}

// ---------------------------------------------------------------------------
extern "C" void kernel_launch(void* const* d_in, const int* in_sizes, int n_in,
                              void* d_out, int out_size, void* d_ws, size_t ws_size,
                              hipStream_t stream) {
    const float* x     = (const float*)d_in[0];
    const int*   ei    = (const int*)d_in[1];
    const float* W1    = (const float*)d_in[2];
    const float* b1    = (const float*)d_in[3];
    const float* beta2 = (const float*)d_in[4];
    const float* W2    = (const float*)d_in[5];
    const float* b2    = (const float*)d_in[6];
    float* out = (float*)d_out;

    const int N = in_sizes[0] / 512;
    const int E = in_sizes[1] / 2;
    const int Etot = E + N;

    char* ws = (char*)d_ws;
    size_t off = 0;
    auto alloc = [&](size_t bytes) -> void* {
        void* p = ws + off;
        off = (off + bytes + 511) & ~(size_t)511;
        return p;
    };
    unsigned char* t1  = (unsigned char*)alloc((size_t)N * 128);       // x_hat1 fp8
    unsigned char* t2  = (unsigned char*)alloc((size_t)N * 128);       // x_hat2 fp8
    unsigned short* h3 = (unsigned short*)alloc((size_t)N * 128 * 2);  // h3 bf16
    float* n1   = (float*)alloc((size_t)N * 4);
    float* n2   = (float*)alloc((size_t)N * 4);
    int* cnt    = (int*)alloc((size_t)N * 4);
    int* rp     = (int*)alloc((size_t)(N + 1) * 4);
    int* cursor = (int*)alloc((size_t)N * 4);
    int* bsum   = (int*)alloc(4096);
    unsigned short* W1t = (unsigned short*)alloc(512 * 128 * 2);
    unsigned short* W2t = (unsigned short*)alloc(128 * 64 * 2);
    int* esrc   = (int*)alloc((size_t)Etot * 4);
    (void)ws_size; (void)n_in; (void)out_size;

    (void)hipMemsetAsync(cnt, 0, (size_t)N * 4, stream);

    k_hist<<<divup(E, 256), 256, 0, stream>>>(ei, E, cnt);
    int nb = divup(N, 1024);
    k_scan1<<<nb, 1024, 0, stream>>>(cnt, N, rp, bsum);
    k_scan2<<<1, 64, 0, stream>>>(bsum, nb);
    k_scan3<<<divup(N + 1, 256), 256, 0, stream>>>(rp, bsum, N, Etot, cursor);
    k_scatter<<<2048, 256, 0, stream>>>(ei, E, N, cursor, esrc);

    k_cvtW<<<divup(512 * 128, 256), 256, 0, stream>>>(W1, W2, W1t, W2t);

    k_gemm1<<<divup(N, 64), 256, 0, stream>>>(x, W1t, b1, N, t1, n1);
    k_conv<<<divup(N, 4), 256, 0, stream>>>(t1, n1, rp, esrc, N, nullptr, t2, n2, nullptr);
    k_conv<<<divup(N, 4), 256, 0, stream>>>(t2, n2, rp, esrc, N, beta2, nullptr, nullptr, h3);
    k_gemm2<<<divup(N, 128), 256, 0, stream>>>(h3, W2t, b2, N, out);
}

// Round 19
// 376.124 us; speedup vs baseline: 1.1345x; 1.0004x over previous
//
#include <hip/hip_runtime.h>
#include <hip/hip_fp8.h>
#include <math.h>

// ---------------------------------------------------------------------------
// AGNN round 19: replace hipMemsetAsync(cnt) with a custom k_zero kernel.
// r18 counters show the 400KB fill dispatch at ~117us (3.4 GB/s) in graph
// replay -- either a real runtime fill-path cost (~31% of total!) or a
// profiling artifact. This swap decides it at near-zero risk.
// All other kernels byte-identical to r18 (verified best, 376.3us).
// ---------------------------------------------------------------------------

static inline int divup(int a, int b) { return (a + b - 1) / b; }

typedef __attribute__((ext_vector_type(8))) short short8;
typedef __attribute__((ext_vector_type(4))) float f32x4;
union U16 { uint4 u; short8 s; };

__device__ __forceinline__ unsigned bf16r(float f) {  // f32 -> bf16 bits, RNE
    unsigned u = __float_as_uint(f);
    return (u + 0x7FFFu + ((u >> 16) & 1u)) >> 16;
}
__device__ __forceinline__ unsigned pack2(float a, float b) {
    return bf16r(a) | (bf16r(b) << 16);
}
__device__ __forceinline__ float bflo(unsigned u) { return __uint_as_float(u << 16); }
__device__ __forceinline__ float bfhi(unsigned u) { return __uint_as_float(u & 0xFFFF0000u); }

__device__ __forceinline__ unsigned char fp8e(float f) {
    __hip_fp8_e4m3 q(f);
    return (unsigned char)q.__x;
}
__device__ __forceinline__ float fp8d(unsigned char b) {
    __hip_fp8_e4m3 q;
    q.__x = (__hip_fp8_storage_t)b;
    return (float)q;
}
__device__ __forceinline__ void unpf8(uint2 u, float* v) {
    const unsigned char* b = (const unsigned char*)&u;
#pragma unroll
    for (int i = 0; i < 8; ++i) v[i] = fp8d(b[i]);
}

// --- zero the histogram (replaces hipMemsetAsync) --------------------------
__global__ __launch_bounds__(256) void k_zero(int* __restrict__ p, int n) {
    int i = blockIdx.x * blockDim.x + threadIdx.x;
    if (i < n) p[i] = 0;
}

// per-block int64/int32 layout autodetect (deterministic across blocks)
__device__ __forceinline__ int edge_flag(const int* raw) {
    __shared__ int sflag;
    if (threadIdx.x < 64) {
        int v = raw[2 * threadIdx.x + 1];
        unsigned long long b = __ballot(v != 0);
        if (threadIdx.x == 0) sflag = (b == 0ULL) ? 1 : 0;  // 1 => int64
    }
    __syncthreads();
    return sflag;
}
__device__ __forceinline__ int edge_src(const int* raw, int E, int flag, int i) {
    return flag ? raw[2 * (size_t)i] : raw[i];
}
__device__ __forceinline__ int edge_dst(const int* raw, int E, int flag, int i) {
    return flag ? raw[2 * ((size_t)E + i)] : raw[(size_t)E + i];
}

// --- histogram straight off raw edge_index ---------------------------------
__global__ __launch_bounds__(256) void k_hist(const int* __restrict__ raw, int E,
                                              int* __restrict__ cnt) {
    int flag = edge_flag(raw);
    int i = blockIdx.x * blockDim.x + threadIdx.x;
    if (i >= E) return;
    atomicAdd(&cnt[edge_dst(raw, E, flag, i)], 1);
}

// --- CSR scan (cnt + 1 self-loop per node) ---------------------------------
__global__ __launch_bounds__(1024) void k_scan1(const int* __restrict__ cnt, int N,
                                                int* __restrict__ rp, int* __restrict__ bsum) {
    __shared__ int sm[1024];
    int t = threadIdx.x;
    int i = blockIdx.x * 1024 + t;
    int v = (i < N) ? cnt[i] + 1 : 0;  // +1: self-loop
    sm[t] = v;
    __syncthreads();
#pragma unroll
    for (int off = 1; off < 1024; off <<= 1) {
        int u = (t >= off) ? sm[t - off] : 0;
        __syncthreads();
        sm[t] += u;
        __syncthreads();
    }
    if (i < N) rp[i] = sm[t] - v;  // exclusive
    if (t == 1023) bsum[blockIdx.x] = sm[t];
}

__global__ __launch_bounds__(64) void k_scan2(int* __restrict__ bsum, int nb) {
    if (threadIdx.x == 0) {
        int run = 0;
        for (int i = 0; i < nb; ++i) { int v = bsum[i]; bsum[i] = run; run += v; }
    }
}

__global__ __launch_bounds__(256) void k_scan3(int* __restrict__ rp, const int* __restrict__ bsum,
                                               int N, int Etot, int* __restrict__ cursor) {
    int i = blockIdx.x * blockDim.x + threadIdx.x;
    if (i < N) {
        int v = rp[i] + bsum[i >> 10];
        rp[i] = v;
        cursor[i] = v;
    } else if (i == N) {
        rp[N] = Etot;
    }
}

// --- XCD-partitioned scatter straight off raw edge_index -------------------
__global__ __launch_bounds__(256) void k_scatter(const int* __restrict__ raw, int E, int N,
                                                 int* __restrict__ cursor,
                                                 int* __restrict__ esrc) {
    int flag = edge_flag(raw);
    int b = blockIdx.x;
    int xcd = b & 7;
    int nstripe = gridDim.x >> 3;
    int stripe = b >> 3;
    int lo = (int)(((long long)xcd * N) >> 3);
    int hi = (int)(((long long)(xcd + 1) * N) >> 3);
    int Etot = E + N;
    for (int e = stripe * 256 + threadIdx.x; e < Etot; e += nstripe * 256) {
        int d = (e < E) ? edge_dst(raw, E, flag, e) : (e - E);
        if (d < lo || d >= hi) continue;
        int s = (e < E) ? edge_src(raw, E, flag, e) : d;
        int pos = atomicAdd(&cursor[d], 1);
        esrc[pos] = s;
    }
}

// --- weight preconvert (merged W1+W2) --------------------------------------
__global__ __launch_bounds__(256) void k_cvtW(const float* __restrict__ W1,
                                              const float* __restrict__ W2,
                                              unsigned short* __restrict__ W1t,
                                              unsigned short* __restrict__ W2t) {
    int i = blockIdx.x * 256 + threadIdx.x;
    if (i < 512 * 128) {
        int k = i >> 7, n = i & 127;
        W1t[n * 512 + k] = (unsigned short)bf16r(W1[i]);
    }
    if (i < 128 * 64) {
        int k = i >> 6, n = i & 63;
        W2t[n * 128 + k] = (unsigned short)bf16r(W2[i]);
    }
}

// --- GEMM1: x_hat1(fp8)/norm1 = normalize(relu(x @ W1 + b1)) ---------------
// 64-row tile, W-resident in 4 phases of 128k (32KB LDS),
// A-stream: loop-carried 4-slot modulo pipeline (r15, verified).
#define XSW(c, off) ((off) ^ (((c) & 7) << 4))
__global__ __launch_bounds__(256) void k_gemm1(const float* __restrict__ x,
                                               const unsigned short* __restrict__ W1t,
                                               const float* __restrict__ b1, int N,
                                               unsigned char* __restrict__ xh1,
                                               float* __restrict__ n1) {
    __shared__ __align__(16) unsigned char lds[32768];
    const int tid = threadIdx.x;
    const int lane = tid & 63;
    const int lt = lane & 15, lg = lane >> 4;
    const int w = tid >> 6;
    const int row0 = blockIdx.x * 64;

    int arow = row0 + w * 16 + lt;
    if (arow > N - 1) arow = N - 1;
    const float* xb = x + (size_t)arow * 512 + lg * 8;

    f32x4 acc[8];
#pragma unroll
    for (int j = 0; j < 8; ++j) acc[j] = (f32x4){0.f, 0.f, 0.f, 0.f};

    float4 buf[4][2];
#pragma unroll
    for (int j = 0; j < 4; ++j) {
        buf[j][0] = ((const float4*)(xb + j * 32))[0];
        buf[j][1] = ((const float4*)(xb + j * 32))[1];
    }

#pragma unroll 1
    for (int kt = 0; kt < 4; ++kt) {
        const int kb = kt * 128;
        __syncthreads();
        {
            int c = tid >> 1, h = tid & 1;
            const uint4* wp = (const uint4*)(W1t + c * 512 + kb + h * 64);
            unsigned char* base = lds + c * 256;
#pragma unroll
            for (int i = 0; i < 8; ++i)
                *(uint4*)(base + XSW(c, h * 128 + i * 16)) = wp[i];
        }
        __syncthreads();

        const bool more = kt < 3;
#pragma unroll
        for (int j = 0; j < 4; ++j) {
            U16 af;
            af.u.x = pack2(buf[j][0].x, buf[j][0].y);
            af.u.y = pack2(buf[j][0].z, buf[j][0].w);
            af.u.z = pack2(buf[j][1].x, buf[j][1].y);
            af.u.w = pack2(buf[j][1].z, buf[j][1].w);
            if (more) {
                const float* np = xb + (kt + 1) * 128 + j * 32;
                buf[j][0] = ((const float4*)np)[0];
                buf[j][1] = ((const float4*)np)[1];
            }
#pragma unroll
            for (int cf = 0; cf < 8; ++cf) {
                int col = cf * 16 + lt;
                U16 bf;
                bf.u = *(const uint4*)(lds + col * 256 + XSW(col, j * 64 + lg * 16));
                acc[cf] = __builtin_amdgcn_mfma_f32_16x16x32_bf16(
                    af.s, bf.s, acc[cf], 0, 0, 0);
            }
        }
    }

    float bias[8];
#pragma unroll
    for (int cf = 0; cf < 8; ++cf) bias[cf] = b1[cf * 16 + lt];
    float* sc = (float*)lds;              // 32 rows x 132 f32 = 16896B
    unsigned char* pk = lds + 16896;      // 32 rows x 144B = 4608B
#pragma unroll 1
    for (int p = 0; p < 2; ++p) {
        __syncthreads();
        if ((w >> 1) == p) {
#pragma unroll
            for (int reg = 0; reg < 4; ++reg) {
                int rl = (w & 1) * 16 + lg * 4 + reg;
#pragma unroll
                for (int cf = 0; cf < 8; ++cf)
                    sc[rl * 132 + cf * 16 + lt] =
                        fmaxf(acc[cf][reg] + bias[cf], 0.f);
            }
        }
        __syncthreads();
        {
            int rl = tid >> 3, q = tid & 7;
            int gr = row0 + p * 32 + rl;
            const float* rowp = sc + rl * 132 + q * 16;
            float v[16];
#pragma unroll
            for (int i = 0; i < 4; ++i) {
                float4 f = ((const float4*)rowp)[i];
                v[4 * i] = f.x; v[4 * i + 1] = f.y; v[4 * i + 2] = f.z; v[4 * i + 3] = f.w;
            }
            float s2 = 0.f;
#pragma unroll
            for (int i = 0; i < 16; ++i) s2 += v[i] * v[i];
            s2 += __shfl_xor(s2, 1, 64);
            s2 += __shfl_xor(s2, 2, 64);
            s2 += __shfl_xor(s2, 4, 64);
            float nrm = sqrtf(s2);
            float rn = 1.0f / fmaxf(nrm, 1e-12f);
            union { unsigned char b[16]; uint4 u; } O;
#pragma unroll
            for (int i = 0; i < 16; ++i) O.b[i] = fp8e(v[i] * rn);
            *(uint4*)(pk + rl * 144 + q * 16) = O.u;
            if (q == 0 && gr < N) n1[gr] = nrm;
        }
        __syncthreads();
        {
            int boff = tid * 16;
            int r = boff >> 7;
            int inner = boff & 127;
            int gr = row0 + p * 32 + r;
            if (gr < N)
                *(uint4*)(xh1 + (size_t)gr * 128 + inner) =
                    *(const uint4*)(pk + r * 144 + inner);
        }
    }
}

// --- AGNN conv: fp8; 16 lanes/edge x 4 edges; chunked idx batch; 2-deep ----
__global__ __launch_bounds__(256) void k_conv(const unsigned char* __restrict__ xh,
                                              const float* __restrict__ nrmt,
                                              const int* __restrict__ rp,
                                              const int* __restrict__ esrc, int N,
                                              const float* __restrict__ betap,
                                              unsigned char* __restrict__ outf8,
                                              float* __restrict__ outn,
                                              unsigned short* __restrict__ outbf) {
    int node = (blockIdx.x * blockDim.x + threadIdx.x) >> 6;
    if (node >= N) return;
    int lane = threadIdx.x & 63;
    int t = lane & 15, g = lane >> 4;
    float beta = betap ? *betap : 1.0f;

    uint2 hdu = *(const uint2*)&xh[(size_t)node * 128 + 8 * t];
    float hd[8];
    unpf8(hdu, hd);

    int e0 = rp[node], e1 = rp[node + 1];
    float acc[8] = {0.f, 0.f, 0.f, 0.f, 0.f, 0.f, 0.f, 0.f};
    float ssum = 0.f;

    for (int cs = e0; cs < e1; cs += 64) {
        int el = cs + lane;
        int sidx = esrc[(el < e1) ? el : e0];
        float nsl = nrmt[sidx];
        int R = e1 - cs;
        if (R > 64) R = 64;
        int nr = (R + 3) >> 2;

        int sA = __shfl(sidx, g, 64);
        float nsA = __shfl(nsl, g, 64);
        uint2 rowA = *(const uint2*)&xh[(size_t)sA * 128 + 8 * t];

        for (int r = 0; r < nr; ++r) {
            const bool hasNext = (r + 1) < nr;
            uint2 rowB;
            float nsB = 0.f;
            if (hasNext) {
                int sB = __shfl(sidx, 4 * (r + 1) + g, 64);
                nsB = __shfl(nsl, 4 * (r + 1) + g, 64);
                rowB = *(const uint2*)&xh[(size_t)sB * 128 + 8 * t];
            }
            float v[8];
            unpf8(rowA, v);
            float p = 0.f;
#pragma unroll
            for (int j = 0; j < 8; ++j) p += v[j] * hd[j];
            p += __shfl_xor(p, 1, 64);
            p += __shfl_xor(p, 2, 64);
            p += __shfl_xor(p, 4, 64);
            p += __shfl_xor(p, 8, 64);
            int e = cs + 4 * r + g;
            float w = (e < e1) ? __expf(p * beta) : 0.f;
            float wn = w * nsA;
            ssum += w;
#pragma unroll
            for (int j = 0; j < 8; ++j) acc[j] += wn * v[j];
            if (hasNext) {
                rowA = rowB;
                nsA = nsB;
            }
        }
    }
#pragma unroll
    for (int j = 0; j < 8; ++j) {
        acc[j] += __shfl_xor(acc[j], 16, 64);
        acc[j] += __shfl_xor(acc[j], 32, 64);
    }
    ssum += __shfl_xor(ssum, 16, 64);
    ssum += __shfl_xor(ssum, 32, 64);
    float r = 1.0f / ssum;

    if (outbf != nullptr) {
        if (g == 0) {
            uint4 q;
            q.x = pack2(acc[0] * r, acc[1] * r);
            q.y = pack2(acc[2] * r, acc[3] * r);
            q.z = pack2(acc[4] * r, acc[5] * r);
            q.w = pack2(acc[6] * r, acc[7] * r);
            *(uint4*)&outbf[(size_t)node * 128 + 8 * t] = q;
        }
    } else {
        float o[8];
        float s2 = 0.f;
#pragma unroll
        for (int j = 0; j < 8; ++j) { o[j] = acc[j] * r; s2 += o[j] * o[j]; }
        s2 += __shfl_xor(s2, 1, 64);
        s2 += __shfl_xor(s2, 2, 64);
        s2 += __shfl_xor(s2, 4, 64);
        s2 += __shfl_xor(s2, 8, 64);
        float nn = sqrtf(s2);
        float rn = 1.0f / fmaxf(nn, 1e-12f);
        if (g == 0) {
            union { unsigned char b[8]; uint2 u; } O;
#pragma unroll
            for (int j = 0; j < 8; ++j) O.b[j] = fp8e(o[j] * rn);
            *(uint2*)&outf8[(size_t)node * 128 + 8 * t] = O.u;
            if (t == 0) outn[node] = nn;
        }
    }
}

// --- GEMM2 (MFMA) + fused log_softmax --------------------------------------
#define G2_ASTRIDE 272
__global__ __launch_bounds__(256) void k_gemm2(const unsigned short* __restrict__ h,
                                               const unsigned short* __restrict__ W2t,
                                               const float* __restrict__ b2, int N,
                                               float* __restrict__ out) {
    __shared__ __align__(16) unsigned char As[128 * G2_ASTRIDE];
    __shared__ __align__(16) unsigned char Bs[64 * G2_ASTRIDE];
    const int tid = threadIdx.x;
    const int lane = tid & 63;
    const int lt = lane & 15, lg = lane >> 4;
    const int wid = tid >> 6;
    const int row0 = blockIdx.x * 128;

    {
        int arow = tid >> 1, ahalf = tid & 1;
        const uint4* src = (const uint4*)(h + (size_t)(row0 + arow) * 128 + ahalf * 64);
        unsigned char* ab = As + arow * G2_ASTRIDE + ahalf * 128;
#pragma unroll
        for (int i = 0; i < 8; ++i) ((uint4*)ab)[i] = src[i];
        int brow = tid >> 2, bq = tid & 3;
        const uint4* bs = (const uint4*)(W2t + (size_t)brow * 128 + bq * 32);
        unsigned char* bb = Bs + brow * G2_ASTRIDE + bq * 64;
#pragma unroll
        for (int i = 0; i < 4; ++i) ((uint4*)bb)[i] = bs[i];
    }
    __syncthreads();

    f32x4 acc[2][4];
#pragma unroll
    for (int i = 0; i < 2; ++i)
#pragma unroll
        for (int j = 0; j < 4; ++j) acc[i][j] = (f32x4){0.f, 0.f, 0.f, 0.f};

#pragma unroll
    for (int sub = 0; sub < 4; ++sub) {
        U16 af[2], bf[4];
#pragma unroll
        for (int mi = 0; mi < 2; ++mi)
            af[mi].u = *(const uint4*)(As + (wid * 32 + mi * 16 + lt) * G2_ASTRIDE + sub * 64 + lg * 16);
#pragma unroll
        for (int ni = 0; ni < 4; ++ni)
            bf[ni].u = *(const uint4*)(Bs + (ni * 16 + lt) * G2_ASTRIDE + sub * 64 + lg * 16);
#pragma unroll
        for (int mi = 0; mi < 2; ++mi)
#pragma unroll
            for (int ni = 0; ni < 4; ++ni)
                acc[mi][ni] = __builtin_amdgcn_mfma_f32_16x16x32_bf16(
                    af[mi].s, bf[ni].s, acc[mi][ni], 0, 0, 0);
    }

    float bias[4];
#pragma unroll
    for (int ni = 0; ni < 4; ++ni) bias[ni] = b2[ni * 16 + lt];

#pragma unroll
    for (int mi = 0; mi < 2; ++mi) {
#pragma unroll
        for (int reg = 0; reg < 4; ++reg) {
            int row = row0 + wid * 32 + mi * 16 + lg * 4 + reg;
            if (row < N) {
                float v[4];
#pragma unroll
                for (int ni = 0; ni < 4; ++ni) v[ni] = acc[mi][ni][reg] + bias[ni];
                float m = fmaxf(fmaxf(v[0], v[1]), fmaxf(v[2], v[3]));
                m = fmaxf(m, __shfl_xor(m, 1, 64));
                m = fmaxf(m, __shfl_xor(m, 2, 64));
                m = fmaxf(m, __shfl_xor(m, 4, 64));
                m = fmaxf(m, __shfl_xor(m, 8, 64));
                float s = __expf(v[0] - m) + __expf(v[1] - m) +
                          __expf(v[2] - m) + __expf(v[3] - m);
                s += __shfl_xor(s, 1, 64);
                s += __shfl_xor(s, 2, 64);
                s += __shfl_xor(s, 4, 64);
                s += __shfl_xor(s, 8, 64);
                float lg2 = logf(s);
#pragma unroll
                for (int ni = 0; ni < 4; ++ni)
                    out[(size_t)row * 64 + ni * 16 + lt] = v[ni] - m - lg2;
            }
        }
    }
}

// ---------------------------------------------------------------------------
extern "C" void kernel_launch(void* const* d_in, const int* in_sizes, int n_in,
                              void* d_out, int out_size, void* d_ws, size_t ws_size,
                              hipStream_t stream) {
    const float* x     = (const float*)d_in[0];
    const int*   ei    = (const int*)d_in[1];
    const float* W1    = (const float*)d_in[2];
    const float* b1    = (const float*)d_in[3];
    const float* beta2 = (const float*)d_in[4];
    const float* W2    = (const float*)d_in[5];
    const float* b2    = (const float*)d_in[6];
    float* out = (float*)d_out;

    const int N = in_sizes[0] / 512;
    const int E = in_sizes[1] / 2;
    const int Etot = E + N;

    char* ws = (char*)d_ws;
    size_t off = 0;
    auto alloc = [&](size_t bytes) -> void* {
        void* p = ws + off;
        off = (off + bytes + 511) & ~(size_t)511;
        return p;
    };
    unsigned char* t1  = (unsigned char*)alloc((size_t)N * 128);       // x_hat1 fp8
    unsigned char* t2  = (unsigned char*)alloc((size_t)N * 128);       // x_hat2 fp8
    unsigned short* h3 = (unsigned short*)alloc((size_t)N * 128 * 2);  // h3 bf16
    float* n1   = (float*)alloc((size_t)N * 4);
    float* n2   = (float*)alloc((size_t)N * 4);
    int* cnt    = (int*)alloc((size_t)N * 4);
    int* rp     = (int*)alloc((size_t)(N + 1) * 4);
    int* cursor = (int*)alloc((size_t)N * 4);
    int* bsum   = (int*)alloc(4096);
    unsigned short* W1t = (unsigned short*)alloc(512 * 128 * 2);
    unsigned short* W2t = (unsigned short*)alloc(128 * 64 * 2);
    int* esrc   = (int*)alloc((size_t)Etot * 4);
    (void)ws_size; (void)n_in; (void)out_size;

    k_zero<<<divup(N, 256), 256, 0, stream>>>(cnt, N);
    k_hist<<<divup(E, 256), 256, 0, stream>>>(ei, E, cnt);
    int nb = divup(N, 1024);
    k_scan1<<<nb, 1024, 0, stream>>>(cnt, N, rp, bsum);
    k_scan2<<<1, 64, 0, stream>>>(bsum, nb);
    k_scan3<<<divup(N + 1, 256), 256, 0, stream>>>(rp, bsum, N, Etot, cursor);
    k_scatter<<<2048, 256, 0, stream>>>(ei, E, N, cursor, esrc);

    k_cvtW<<<divup(512 * 128, 256), 256, 0, stream>>>(W1, W2, W1t, W2t);

    k_gemm1<<<divup(N, 64), 256, 0, stream>>>(x, W1t, b1, N, t1, n1);
    k_conv<<<divup(N, 4), 256, 0, stream>>>(t1, n1, rp, esrc, N, nullptr, t2, n2, nullptr);
    k_conv<<<divup(N, 4), 256, 0, stream>>>(t2, n2, rp, esrc, N, beta2, nullptr, nullptr, h3);
    k_gemm2<<<divup(N, 128), 256, 0, stream>>>(h3, W2t, b2, N, out);
}